// Round 2
// baseline (141.661 us; speedup 1.0000x reference)
//
#include <hip/hip_runtime.h>
#include <math.h>

// DeterministicLattice: ring-neighbor fusion + 5 correlated nonlinear outputs.
// N=65536 nodes, D=512 -> 33,554,432 f32 in, 5x that out. Memory-bound.

#define NUM_NODES 65536
#define DIM 512

typedef float f32x4 __attribute__((ext_vector_type(4)));

__global__ __launch_bounds__(256) void genesis_kernel(
    const f32x4* __restrict__ x, f32x4* __restrict__ out, int tot4) {
  const float phi      = 1.61803398874989484820f;
  const float inv_phi  = 0.61803398874989484820f;   // 1/phi
  const float inv_p2   = 1.0f / (phi + 2.0f);       // 1/(phi+2)
  const int row4 = DIM / 4;                         // 128 float4 per row

  int stride = gridDim.x * blockDim.x;
  for (int e = blockIdx.x * blockDim.x + threadIdx.x; e < tot4; e += stride) {
    // roll(+1)/roll(-1) on axis 0 == linear offset -/+ row4 with full-array wrap
    int l = e - row4; if (l < 0)     l += tot4;
    int r = e + row4; if (r >= tot4) r -= tot4;

    f32x4 c = x[e];
    f32x4 lv = x[l];
    f32x4 rv = x[r];

    f32x4 v_id, v_bl, v_cr, v_tr, v_sp;
#pragma unroll
    for (int j = 0; j < 4; ++j) {
      float f = (phi * c[j] + lv[j] + rv[j]) * inv_p2;

      // tanh(f) = (e^{2f}-1)/(e^{2f}+1)
      float e2 = __expf(2.0f * f);
      float t = (e2 - 1.0f) * __builtin_amdgcn_rcpf(e2 + 1.0f);

      // ep = e^{phi f}; tanh(phi f) = (ep^2-1)/(ep^2+1); sigmoid(phi f) = ep/(ep+1)
      float ep = __expf(phi * f);
      float ep2 = ep * ep;
      float bloom = (ep2 - 1.0f) * __builtin_amdgcn_rcpf(ep2 + 1.0f);
      float crown = ep * __builtin_amdgcn_rcpf(ep + 1.0f);

      v_id[j] = f + inv_phi * t;
      v_bl[j] = bloom;
      v_cr[j] = crown;
      v_tr[j] = __sinf(f) * __cosf(phi * f);
      v_sp[j] = f * __expf(-fabsf(f) * inv_phi);
    }

    // stack order: [identity_next, bloom, crown, triad, spiral]
    __builtin_nontemporal_store(v_id, &out[0 * (size_t)tot4 + e]);
    __builtin_nontemporal_store(v_bl, &out[1 * (size_t)tot4 + e]);
    __builtin_nontemporal_store(v_cr, &out[2 * (size_t)tot4 + e]);
    __builtin_nontemporal_store(v_tr, &out[3 * (size_t)tot4 + e]);
    __builtin_nontemporal_store(v_sp, &out[4 * (size_t)tot4 + e]);
  }
}

extern "C" void kernel_launch(void* const* d_in, const int* in_sizes, int n_in,
                              void* d_out, int out_size, void* d_ws, size_t ws_size,
                              hipStream_t stream) {
  const f32x4* x = (const f32x4*)d_in[0];
  f32x4* out = (f32x4*)d_out;
  int tot4 = in_sizes[0] / 4;  // 8,388,608 float4 elements

  const int block = 256;
  const int grid = 2048;  // grid-stride; 256 CU * 8 blocks/CU
  genesis_kernel<<<grid, block, 0, stream>>>(x, out, tot4);
}

// Round 3
// 140.875 us; speedup vs baseline: 1.0056x; 1.0056x over previous
//
#include <hip/hip_runtime.h>
#include <math.h>

// DeterministicLattice: ring-neighbor fusion + 5 correlated nonlinear outputs.
// N=65536 nodes, D=512 -> 33,554,432 f32 in, 5x out. Memory-bound.
// Exact-fit launch: one f32x4 per thread, no grid-stride loop (maximize MLP).

#define NUM_NODES 65536
#define DIM 512

typedef float f32x4 __attribute__((ext_vector_type(4)));

__global__ __launch_bounds__(256) void genesis_kernel(
    const f32x4* __restrict__ x, f32x4* __restrict__ out, int tot4) {
  const float phi      = 1.61803398874989484820f;
  const float inv_phi  = 0.61803398874989484820f;   // 1/phi
  const float inv_p2   = 1.0f / (phi + 2.0f);       // 1/(phi+2)
  const int row4 = DIM / 4;                         // 128 f32x4 per row

  int e = blockIdx.x * 256 + threadIdx.x;
  if (e >= tot4) return;

  // roll(+1)/roll(-1) on axis 0 == linear offset -/+ row4 with full-array wrap
  int l = e - row4; if (l < 0)     l += tot4;
  int r = e + row4; if (r >= tot4) r -= tot4;

  f32x4 c = x[e];
  f32x4 lv = x[l];
  f32x4 rv = x[r];

  f32x4 v_id, v_bl, v_cr, v_tr, v_sp;
#pragma unroll
  for (int j = 0; j < 4; ++j) {
    float f = (phi * c[j] + lv[j] + rv[j]) * inv_p2;

    // tanh(f) = (e^{2f}-1)/(e^{2f}+1)
    float e2 = __expf(2.0f * f);
    float t = (e2 - 1.0f) * __builtin_amdgcn_rcpf(e2 + 1.0f);

    // ep = e^{phi f}; tanh(phi f) = (ep^2-1)/(ep^2+1); sigmoid(phi f) = ep/(ep+1)
    float ep = __expf(phi * f);
    float ep2 = ep * ep;
    float bloom = (ep2 - 1.0f) * __builtin_amdgcn_rcpf(ep2 + 1.0f);
    float crown = ep * __builtin_amdgcn_rcpf(ep + 1.0f);

    v_id[j] = f + inv_phi * t;
    v_bl[j] = bloom;
    v_cr[j] = crown;
    v_tr[j] = __sinf(f) * __cosf(phi * f);
    v_sp[j] = f * __expf(-fabsf(f) * inv_phi);
  }

  // stack order: [identity_next, bloom, crown, triad, spiral]
  __builtin_nontemporal_store(v_id, &out[0 * (size_t)tot4 + e]);
  __builtin_nontemporal_store(v_bl, &out[1 * (size_t)tot4 + e]);
  __builtin_nontemporal_store(v_cr, &out[2 * (size_t)tot4 + e]);
  __builtin_nontemporal_store(v_tr, &out[3 * (size_t)tot4 + e]);
  __builtin_nontemporal_store(v_sp, &out[4 * (size_t)tot4 + e]);
}

extern "C" void kernel_launch(void* const* d_in, const int* in_sizes, int n_in,
                              void* d_out, int out_size, void* d_ws, size_t ws_size,
                              hipStream_t stream) {
  const f32x4* x = (const f32x4*)d_in[0];
  f32x4* out = (f32x4*)d_out;
  int tot4 = in_sizes[0] / 4;  // 8,388,608 f32x4 elements

  const int block = 256;
  const int grid = (tot4 + block - 1) / block;  // 32768 blocks, exact fit
  genesis_kernel<<<grid, block, 0, stream>>>(x, out, tot4);
}

// Round 4
// 130.849 us; speedup vs baseline: 1.0826x; 1.0766x over previous
//
#include <hip/hip_runtime.h>
#include <math.h>

// DeterministicLattice: ring-neighbor fusion + 5 correlated nonlinear outputs.
// N=65536 rows, D=512 -> view as [65536][128] f32x4. Memory-bound.
// Vertical 4-row strips per thread: 6 row-loads produce 4 output rows
// (register reuse of shared ring neighbors), 25% halo instead of 100%.

#define N_ROWS 65536
#define COLS4 128  // 512 floats / 4

typedef float f32x4 __attribute__((ext_vector_type(4)));

__global__ __launch_bounds__(256) void genesis_kernel(
    const f32x4* __restrict__ x, f32x4* __restrict__ out) {
  const float phi     = 1.61803398874989484820f;
  const float inv_phi = 0.61803398874989484820f;   // 1/phi
  const float inv_p2  = 1.0f / (phi + 2.0f);       // 1/(phi+2)

  const int t = threadIdx.x;
  const int c = t & 127;            // f32x4 column
  const int rsub = t >> 7;          // 0 or 1: which 4-row band in the block
  const int r0 = blockIdx.x * 8 + rsub * 4;  // first of 4 consecutive rows

  // rows needed: r0-1 .. r0+4, ring wrap on the ends only
  int rm = r0 - 1; if (rm < 0) rm += N_ROWS;
  int rp = r0 + 4; if (rp >= N_ROWS) rp -= N_ROWS;

  f32x4 L0 = x[(size_t)rm * COLS4 + c];
  f32x4 L1 = x[(size_t)(r0 + 0) * COLS4 + c];
  f32x4 L2 = x[(size_t)(r0 + 1) * COLS4 + c];
  f32x4 L3 = x[(size_t)(r0 + 2) * COLS4 + c];
  f32x4 L4 = x[(size_t)(r0 + 3) * COLS4 + c];
  f32x4 L5 = x[(size_t)rp * COLS4 + c];
  f32x4 L[6] = {L0, L1, L2, L3, L4, L5};

  const size_t plane = (size_t)N_ROWS * COLS4;

#pragma unroll
  for (int k = 0; k < 4; ++k) {
    size_t o = (size_t)(r0 + k) * COLS4 + c;
    f32x4 v_id, v_bl, v_cr, v_tr, v_sp;
#pragma unroll
    for (int j = 0; j < 4; ++j) {
      // out row r0+k: center L[k+1], left ring neighbor L[k], right L[k+2]
      float f = (phi * L[k + 1][j] + L[k][j] + L[k + 2][j]) * inv_p2;

      // tanh(f) = (e^{2f}-1)/(e^{2f}+1)
      float e2 = __expf(2.0f * f);
      float tnh = (e2 - 1.0f) * __builtin_amdgcn_rcpf(e2 + 1.0f);

      // ep = e^{phi f}; tanh(phi f) = (ep^2-1)/(ep^2+1); sigmoid(phi f) = ep/(ep+1)
      float ep = __expf(phi * f);
      float ep2 = ep * ep;
      float bloom = (ep2 - 1.0f) * __builtin_amdgcn_rcpf(ep2 + 1.0f);
      float crown = ep * __builtin_amdgcn_rcpf(ep + 1.0f);

      v_id[j] = f + inv_phi * tnh;
      v_bl[j] = bloom;
      v_cr[j] = crown;
      v_tr[j] = __sinf(f) * __cosf(phi * f);
      v_sp[j] = f * __expf(-fabsf(f) * inv_phi);
    }

    // stack order: [identity_next, bloom, crown, triad, spiral]
    __builtin_nontemporal_store(v_id, &out[0 * plane + o]);
    __builtin_nontemporal_store(v_bl, &out[1 * plane + o]);
    __builtin_nontemporal_store(v_cr, &out[2 * plane + o]);
    __builtin_nontemporal_store(v_tr, &out[3 * plane + o]);
    __builtin_nontemporal_store(v_sp, &out[4 * plane + o]);
  }
}

extern "C" void kernel_launch(void* const* d_in, const int* in_sizes, int n_in,
                              void* d_out, int out_size, void* d_ws, size_t ws_size,
                              hipStream_t stream) {
  const f32x4* x = (const f32x4*)d_in[0];
  f32x4* out = (f32x4*)d_out;

  const int block = 256;
  const int grid = N_ROWS / 8;  // 8192 blocks: 8 rows per block
  genesis_kernel<<<grid, block, 0, stream>>>(x, out);
}

// Round 5
// 130.145 us; speedup vs baseline: 1.0885x; 1.0054x over previous
//
#include <hip/hip_runtime.h>
#include <math.h>

// DeterministicLattice: ring-neighbor fusion + 5 correlated nonlinear outputs.
// N=65536 rows, D=512 -> view as [65536][128] f32x4. Memory-bound.
// 8-row strips per thread (10 loads -> 8 output rows, 12.5% block halo) +
// bijective XCD-chunk swizzle so inter-block halo reads hit the same XCD L2.

#define N_ROWS 65536
#define COLS4 128  // 512 floats / 4
#define ROWS_PER_THREAD 8
#define ROWS_PER_BLOCK 16  // 256 threads = 128 cols x 2 bands

typedef float f32x4 __attribute__((ext_vector_type(4)));

__global__ __launch_bounds__(256) void genesis_kernel(
    const f32x4* __restrict__ x, f32x4* __restrict__ out) {
  const float phi     = 1.61803398874989484820f;
  const float inv_phi = 0.61803398874989484820f;   // 1/phi
  const float inv_p2  = 1.0f / (phi + 2.0f);       // 1/(phi+2)

  // bijective XCD swizzle: 4096 blocks, 8 XCDs -> 512 contiguous blocks/XCD
  const int nwg_per_xcd = gridDim.x >> 3;
  int bid = (int)blockIdx.x;
  int swz = (bid & 7) * nwg_per_xcd + (bid >> 3);

  const int t = threadIdx.x;
  const int c = t & 127;            // f32x4 column
  const int rsub = t >> 7;          // 0 or 1: which 8-row band in the block
  const int r0 = swz * ROWS_PER_BLOCK + rsub * ROWS_PER_THREAD;

  // rows needed: r0-1 .. r0+8, ring wrap on the ends only
  int rm = r0 - 1; if (rm < 0) rm += N_ROWS;
  int rp = r0 + ROWS_PER_THREAD; if (rp >= N_ROWS) rp -= N_ROWS;

  f32x4 L[ROWS_PER_THREAD + 2];
  L[0] = x[(size_t)rm * COLS4 + c];
#pragma unroll
  for (int k = 0; k < ROWS_PER_THREAD; ++k)
    L[k + 1] = x[(size_t)(r0 + k) * COLS4 + c];
  L[ROWS_PER_THREAD + 1] = x[(size_t)rp * COLS4 + c];

  const size_t plane = (size_t)N_ROWS * COLS4;

#pragma unroll
  for (int k = 0; k < ROWS_PER_THREAD; ++k) {
    size_t o = (size_t)(r0 + k) * COLS4 + c;
    f32x4 v_id, v_bl, v_cr, v_tr, v_sp;
#pragma unroll
    for (int j = 0; j < 4; ++j) {
      // out row r0+k: center L[k+1], left ring neighbor L[k], right L[k+2]
      float f = (phi * L[k + 1][j] + L[k][j] + L[k + 2][j]) * inv_p2;

      // tanh(f) = (e^{2f}-1)/(e^{2f}+1)
      float e2 = __expf(2.0f * f);
      float tnh = (e2 - 1.0f) * __builtin_amdgcn_rcpf(e2 + 1.0f);

      // ep = e^{phi f}; tanh(phi f) = (ep^2-1)/(ep^2+1); sigmoid(phi f) = ep/(ep+1)
      float ep = __expf(phi * f);
      float ep2 = ep * ep;
      float bloom = (ep2 - 1.0f) * __builtin_amdgcn_rcpf(ep2 + 1.0f);
      float crown = ep * __builtin_amdgcn_rcpf(ep + 1.0f);

      v_id[j] = f + inv_phi * tnh;
      v_bl[j] = bloom;
      v_cr[j] = crown;
      v_tr[j] = __sinf(f) * __cosf(phi * f);
      v_sp[j] = f * __expf(-fabsf(f) * inv_phi);
    }

    // stack order: [identity_next, bloom, crown, triad, spiral]
    __builtin_nontemporal_store(v_id, &out[0 * plane + o]);
    __builtin_nontemporal_store(v_bl, &out[1 * plane + o]);
    __builtin_nontemporal_store(v_cr, &out[2 * plane + o]);
    __builtin_nontemporal_store(v_tr, &out[3 * plane + o]);
    __builtin_nontemporal_store(v_sp, &out[4 * plane + o]);
  }
}

extern "C" void kernel_launch(void* const* d_in, const int* in_sizes, int n_in,
                              void* d_out, int out_size, void* d_ws, size_t ws_size,
                              hipStream_t stream) {
  const f32x4* x = (const f32x4*)d_in[0];
  f32x4* out = (f32x4*)d_out;

  const int block = 256;
  const int grid = N_ROWS / ROWS_PER_BLOCK;  // 4096 blocks, divisible by 8
  genesis_kernel<<<grid, block, 0, stream>>>(x, out);
}